// Round 14
// baseline (1038.326 us; speedup 1.0000x reference)
//
#include <hip/hip_runtime.h>
#include <hip/hip_bf16.h>

#define Dd 1024
#define Ss 256
#define Bz 2
#define Kk 8
#define Vv 32000
#define Ff 2048
#define Ii 248
#define Mm (Bz*Ii)    // 496
#define Mp 512        // padded activation rows
#define Mu (Kk*Mm)    // 3968
#define Mx 4096       // unembed M padded to 256-multiple

typedef __attribute__((ext_vector_type(8))) short bf16x8_t;
typedef __attribute__((ext_vector_type(4))) float f32x4_t;
typedef __attribute__((ext_vector_type(16))) float f32x16_t;
typedef unsigned long long u64;

__device__ inline ushort f2b(float f) {
    union { float f; unsigned u; } v; v.f = f;
    unsigned u = v.u;
    unsigned r = (u + 0x7fffu + ((u >> 16) & 1u)) >> 16;  // RNE
    return (ushort)r;
}

__device__ inline void gload16(const void* g, void* l) {
    __builtin_amdgcn_global_load_lds((const __attribute__((address_space(1))) void*)g,
                                     (__attribute__((address_space(3))) void*)l, 16, 0, 0);
}

template<int N> __device__ inline void wait_vmcnt() {
    asm volatile("s_waitcnt vmcnt(%0)" :: "n"(N) : "memory");
}
__device__ inline void bar() {
    asm volatile("" ::: "memory");
    __builtin_amdgcn_s_barrier();
    asm volatile("" ::: "memory");
}

// XOR swizzle on 16B slots within a row (both-sides-or-neither, rule #21).
template<int BK>
__device__ inline int swz(int s, int r) {
    if constexpr (BK == 64) return s ^ (r & 7);        // 8 slots/row
    else                    return s ^ ((r >> 1) & 3); // BK=32: 4 slots/row
}

// ---------------- fused weight-conversion task table (one launch) ----------------
// Contiguous f32 src -> bf16 dst tasks; sizes multiples of 4096 elems.
// One block = one 4096-elem chunk (256 thr x 16 f32). Machinery validated R10.
#define NTASK 24
struct CvTab {
    u64 src[NTASK];
    u64 dst[NTASK];
    int start[NTASK + 1];   // cumulative chunk index; start[n] = total
    int n;
};

__global__ __launch_bounds__(256)
void convert_all(CvTab tab) {
    const int g = blockIdx.x;
    int lo = 0;
    while (lo + 1 < tab.n && tab.start[lo + 1] <= g) ++lo;   // uniform scalar scan
    const float* s = (const float*)tab.src[lo];
    ushort* d = (ushort*)tab.dst[lo];
    const long e0 = (long)(g - tab.start[lo]) * 4096 + threadIdx.x * 16;
    #pragma unroll
    for (int j = 0; j < 4; ++j) {
        const float4 v = *(const float4*)(s + e0 + j * 4);
        ushort4 h; h.x = f2b(v.x); h.y = f2b(v.y); h.z = f2b(v.z); h.w = f2b(v.w);
        *(ushort4*)(d + e0 + j * 4) = h;
    }
}

// =============== unembed GEMM: 32x32x16 MFMA (R11 best: 256x256/BK=64) ===============
__global__ __launch_bounds__(512, 2)
void gemm32(const ushort* __restrict__ A, const ushort* __restrict__ W,
            float* __restrict__ Cf, int Mrows, int KDIM) {
    constexpr int BM = 256, BN = 256, BK = 64, TH = 512, PF = 2;
    constexpr int TILE = (BM + BN) * BK;        // 64 KB
    constexpr int ABYTES = BM * BK * 2;
    constexpr int L = (BM + BN) * BK * 2 / (TH * 16);  // 8
    __shared__ __align__(16) ushort sm[PF * TILE];     // 128 KB

    int bx = blockIdx.x, by = blockIdx.y;
    {   // bijective XCD-aware swizzle (m204)
        const int nwg  = gridDim.x * gridDim.y;
        const int orig = by * gridDim.x + bx;
        const int q = nwg >> 3, r = nwg & 7;
        const int xcd = orig & 7, lin = orig >> 3;
        const int wg = (xcd < r ? xcd * (q + 1) : r * (q + 1) + (xcd - r) * q) + lin;
        bx = wg % gridDim.x; by = wg / gridDim.x;
    }
    const int t    = threadIdx.x;
    const int lane = t & 63;
    const int w    = t >> 6;
    const int wr   = (w >> 2) * 128;            // wave grid 2 x 4
    const int wc   = (w & 3) * 64;
    const int tm0  = bx * BM, tn0 = by * BN;

    const ushort* Abase = A + (size_t)tm0 * KDIM;
    const ushort* Wbase = W + (size_t)tn0 * KDIM;

    const ushort* gp[L]; int lo[L];
    #pragma unroll
    for (int j = 0; j < L; ++j) {
        const int i = (t + j * TH) * 16;
        int r, s; const ushort* base;
        if (i < ABYTES) { r = i / (BK * 2); s = (i >> 4) % (BK / 8); base = Abase; }
        else { const int i2 = i - ABYTES; r = i2 / (BK * 2); s = (i2 >> 4) % (BK / 8); base = Wbase; }
        gp[j] = base + (size_t)r * KDIM + (size_t)swz<BK>(s, r) * 8;
        lo[j] = i / 2;
    }
    auto stage = [&](int buf) {
        #pragma unroll
        for (int j = 0; j < L; ++j) gload16(gp[j], &sm[buf * TILE + lo[j]]);
        #pragma unroll
        for (int j = 0; j < L; ++j) gp[j] += BK;
    };

    const int rl = lane & 31, hk = lane >> 5;
    int aoff[4][4], boff[2][4];
    #pragma unroll
    for (int m = 0; m < 4; ++m)
        #pragma unroll
        for (int ks = 0; ks < 4; ++ks) {
            const int r = wr + m * 32 + rl;
            aoff[m][ks] = r * BK + swz<BK>(ks * 2 + hk, r) * 8;
        }
    #pragma unroll
    for (int n = 0; n < 2; ++n)
        #pragma unroll
        for (int ks = 0; ks < 4; ++ks) {
            const int r = wc + n * 32 + rl;
            boff[n][ks] = BM * BK + r * BK + swz<BK>(ks * 2 + hk, r) * 8;
        }

    f32x16_t acc[4][2] = {};
    const int NT = KDIM / BK;                   // 16

    stage(0); stage(1);
    int buf = 0;
    for (int kt = 0; kt < NT; ++kt) {
        const int remT = NT - 1 - kt;
        if (remT >= 1) wait_vmcnt<L>(); else wait_vmcnt<0>();
        bar();

        const ushort* smb = &sm[buf * TILE];
        #pragma unroll
        for (int ks = 0; ks < 4; ++ks) {
            bf16x8_t af[4], bf[2];
            #pragma unroll
            for (int m = 0; m < 4; ++m) af[m] = *(const bf16x8_t*)&smb[aoff[m][ks]];
            #pragma unroll
            for (int n = 0; n < 2; ++n) bf[n] = *(const bf16x8_t*)&smb[boff[n][ks]];
            #pragma unroll
            for (int m = 0; m < 4; ++m)
                #pragma unroll
                for (int n = 0; n < 2; ++n)
                    acc[m][n] = __builtin_amdgcn_mfma_f32_32x32x16_bf16(af[m], bf[n], acc[m][n], 0, 0, 0);
        }
        bar();
        if (kt + PF < NT) stage(buf);
        buf ^= 1;
    }

    // C/D: col=lane&31, row=(reg&3)+8*(reg>>2)+4*(lane>>5)  [m74/m101]
    const int cl = lane & 31;
    #pragma unroll
    for (int m = 0; m < 4; ++m)
        #pragma unroll
        for (int n = 0; n < 2; ++n)
            #pragma unroll
            for (int reg = 0; reg < 16; ++reg) {
                const int row = (reg & 3) + 8 * (reg >> 2) + 4 * hk;
                const int r = tm0 + wr + m * 32 + row;
                const int c = tn0 + wc + n * 32 + cl;
                if (r < Mrows) {
                    const int kk  = r / Mm;
                    const int rem = r - kk * Mm;
                    __builtin_nontemporal_store(acc[m][n][reg],
                        &Cf[(size_t)(rem * Kk + kk) * Vv + c]);
                }
            }
}

// ---------------- counted-vmcnt PF-deep bf16 GEMM (chain, proven R8/R11) ----------------
template<int BM, int BN, int BK, int TH, int PF, bool RELU, bool UNEMBED>
__global__ __launch_bounds__(TH, 2)
void gemm3(const ushort* __restrict__ A0, const ushort* __restrict__ A1, int lda,
           const ushort* __restrict__ W0, const ushort* __restrict__ W1,
           const float* __restrict__ b0, const float* __restrict__ b1,
           float* __restrict__ Cf0, float* __restrict__ Cf1,
           ushort* __restrict__ Cb0, ushort* __restrict__ Cb1,
           int Mrows, int N, int KDIM) {
    constexpr int NW = TH / 64;
    constexpr int WN = NW / 2;
    constexpr int MR = (BM / 2) / 16;
    constexpr int NR = (BN / WN) / 16;
    constexpr int TILE = (BM + BN) * BK;
    constexpr int ABYTES = BM * BK * 2;
    constexpr int TOT = (BM + BN) * BK * 2;
    constexpr int L = TOT / (TH * 16);
    constexpr int KS = BK / 32;

    __shared__ __align__(16) ushort sm[PF * TILE];

    const ushort* A = A0; const ushort* W = W0; const float* bias = b0;
    float* Cf = Cf0; ushort* Cb = Cb0;
    if (blockIdx.z) { A = A1; W = W1; bias = b1; Cf = Cf1; Cb = Cb1; }

    const int t    = threadIdx.x;
    const int tm0  = blockIdx.x * BM;
    const int tn0  = blockIdx.y * BN;
    const int lane = t & 63;
    const int w    = t >> 6;
    const int wr   = (w / WN) * (BM / 2);
    const int wc   = (w % WN) * (BN / WN);

    const ushort* Abase = A + (size_t)tm0 * lda;
    const ushort* Wbase = W + (size_t)tn0 * KDIM;

    const ushort* gp[L];
    int lo[L];
    #pragma unroll
    for (int j = 0; j < L; ++j) {
        const int i = (t + j * TH) * 16;
        int r, s; const ushort* base; int ld;
        if (i < ABYTES) { r = i / (BK * 2); s = (i >> 4) % (BK / 8); base = Abase; ld = lda; }
        else { const int i2 = i - ABYTES; r = i2 / (BK * 2); s = (i2 >> 4) % (BK / 8); base = Wbase; ld = KDIM; }
        gp[j] = base + (size_t)r * ld + swz<BK>(s, r) * 8;
        lo[j] = i / 2;
    }
    auto stage = [&](int buf) {
        #pragma unroll
        for (int j = 0; j < L; ++j) gload16(gp[j], &sm[buf * TILE + lo[j]]);
        #pragma unroll
        for (int j = 0; j < L; ++j) gp[j] += BK;
    };

    const int h = lane >> 4, rl = lane & 15;
    int aoff[MR][KS], boff[NR][KS];
    #pragma unroll
    for (int m = 0; m < MR; ++m)
        #pragma unroll
        for (int kk = 0; kk < KS; ++kk) {
            const int r = wr + m * 16 + rl;
            aoff[m][kk] = r * BK + swz<BK>(kk * 4 + h, r) * 8;
        }
    #pragma unroll
    for (int n = 0; n < NR; ++n)
        #pragma unroll
        for (int kk = 0; kk < KS; ++kk) {
            const int r = wc + n * 16 + rl;
            boff[n][kk] = BM * BK + r * BK + swz<BK>(kk * 4 + h, r) * 8;
        }

    f32x4_t acc[MR][NR] = {};

    const int NT = KDIM / BK;
    #pragma unroll
    for (int p = 0; p < PF; ++p) stage(p);

    int buf = 0;
    for (int kt = 0; kt < NT; ++kt) {
        const int remT = NT - 1 - kt;
        const int wv = remT < PF - 1 ? remT : PF - 1;
        switch (wv) {
            case 0:  wait_vmcnt<0>();     break;
            case 1:  wait_vmcnt<1 * L>(); break;
            case 2:  wait_vmcnt<2 * L>(); break;
            default: wait_vmcnt<3 * L>(); break;
        }
        bar();

        const ushort* smb = &sm[buf * TILE];
        #pragma unroll
        for (int kk = 0; kk < KS; ++kk) {
            bf16x8_t af[MR], bf[NR];
            #pragma unroll
            for (int m = 0; m < MR; ++m) af[m] = *(const bf16x8_t*)&smb[aoff[m][kk]];
            #pragma unroll
            for (int n = 0; n < NR; ++n) bf[n] = *(const bf16x8_t*)&smb[boff[n][kk]];
            #pragma unroll
            for (int m = 0; m < MR; ++m)
                #pragma unroll
                for (int n = 0; n < NR; ++n)
                    acc[m][n] = __builtin_amdgcn_mfma_f32_16x16x32_bf16(af[m], bf[n], acc[m][n], 0, 0, 0);
        }
        bar();
        if (kt + PF < NT) stage(buf);
        buf = (buf + 1 == PF) ? 0 : buf + 1;
    }

    const int rb = (lane >> 4) * 4;
    const int cl = lane & 15;
    #pragma unroll
    for (int m = 0; m < MR; ++m)
        #pragma unroll
        for (int n = 0; n < NR; ++n)
            #pragma unroll
            for (int i = 0; i < 4; ++i) {
                const int r = tm0 + wr + m * 16 + rb + i;
                const int c = tn0 + wc + n * 16 + cl;
                if (r < Mrows) {
                    float v = acc[m][n][i];
                    if (bias) v += bias[c];
                    if (RELU) v = fmaxf(v, 0.f);
                    if (UNEMBED) {
                        const int kk  = r / Mm;
                        const int rem = r - kk * Mm;
                        Cf[(size_t)(rem * Kk + kk) * Vv + c] = v;
                    } else {
                        if (Cf) Cf[(size_t)r * N + c] = v;
                        if (Cb) Cb[(size_t)r * N + c] = f2b(v);
                    }
                }
            }
}

// ---------------- small copies ----------------
__global__ __launch_bounds__(256)
void copyf_k(const float* __restrict__ src, float* __restrict__ dst,
             long n, long perK, long dstPerK, long dstOff) {
    long i = (long)blockIdx.x * 256 + threadIdx.x;
    const long stride = (long)gridDim.x * 256;
    for (; i < n; i += stride) {
        const long k = i / perK, rem = i - k * perK;
        dst[k * dstPerK + dstOff + rem] = src[i];
    }
}

// ---------------- fused elementwise kernels ----------------

__global__ __launch_bounds__(256)
void ln12_kernel(const float* __restrict__ sa, const float* __restrict__ xp,
                 const float* __restrict__ ca,
                 const float* __restrict__ g1, const float* __restrict__ b1,
                 const float* __restrict__ g2, const float* __restrict__ b2,
                 float* __restrict__ x2f, ushort* __restrict__ x2b) {
    __shared__ float reds[16];
    const int row = blockIdx.x;
    const int t = threadIdx.x;
    const float4 va = *(const float4*)(sa + (size_t)row * Dd + t * 4);
    const float4 vp = *(const float4*)(xp + (size_t)row * Dd + t * 4);
    float x[4] = { va.x + vp.x, va.y + vp.y, va.z + vp.z, va.w + vp.w };
    float s = x[0] + x[1] + x[2] + x[3];
    float q = x[0]*x[0] + x[1]*x[1] + x[2]*x[2] + x[3]*x[3];
    for (int m = 32; m; m >>= 1) { s += __shfl_xor(s, m); q += __shfl_xor(q, m); }
    if ((t & 63) == 0) { reds[t >> 6] = s; reds[4 + (t >> 6)] = q; }
    __syncthreads();
    s = reds[0] + reds[1] + reds[2] + reds[3];
    q = reds[4] + reds[5] + reds[6] + reds[7];
    float mean = s * (1.f / Dd);
    float rstd = rsqrtf(q * (1.f / Dd) - mean * mean + 1e-5f);
    const float4 vc = *(const float4*)(ca + (size_t)row * Dd + t * 4);
    float y[4];
    #pragma unroll
    for (int j = 0; j < 4; ++j) {
        const int c = t * 4 + j;
        y[j] = (x[j] - mean) * rstd * g1[c] + b1[c] + ((const float*)&vc)[j];
    }
    s = y[0] + y[1] + y[2] + y[3];
    q = y[0]*y[0] + y[1]*y[1] + y[2]*y[2] + y[3]*y[3];
    for (int m = 32; m; m >>= 1) { s += __shfl_xor(s, m); q += __shfl_xor(q, m); }
    if ((t & 63) == 0) { reds[8 + (t >> 6)] = s; reds[12 + (t >> 6)] = q; }
    __syncthreads();
    s = reds[8] + reds[9] + reds[10] + reds[11];
    q = reds[12] + reds[13] + reds[14] + reds[15];
    mean = s * (1.f / Dd);
    rstd = rsqrtf(q * (1.f / Dd) - mean * mean + 1e-5f);
    float z[4]; ushort4 hb;
    #pragma unroll
    for (int j = 0; j < 4; ++j) {
        const int c = t * 4 + j;
        z[j] = (y[j] - mean) * rstd * g2[c] + b2[c];
    }
    hb.x = f2b(z[0]); hb.y = f2b(z[1]); hb.z = f2b(z[2]); hb.w = f2b(z[3]);
    *(float4*)(x2f + (size_t)row * Dd + t * 4) = make_float4(z[0], z[1], z[2], z[3]);
    *(ushort4*)(x2b + (size_t)row * Dd + t * 4) = hb;
}

__global__ __launch_bounds__(256)
void ln3m_kernel(const float* __restrict__ ff, const float* __restrict__ x2,
                 const float* __restrict__ g3, const float* __restrict__ b3,
                 const ushort* __restrict__ remb, ushort* __restrict__ x3k,
                 ushort* __restrict__ merged, int k) {
    __shared__ float reds[12];
    const int r = blockIdx.x;
    const int t = threadIdx.x;
    const int b = r / Ii, i = r - b * Ii;
    const float4 vf = *(const float4*)(ff + (size_t)r * Dd + t * 4);
    const float4 v2 = *(const float4*)(x2 + (size_t)r * Dd + t * 4);
    float x[4] = { vf.x + v2.x, vf.y + v2.y, vf.z + v2.z, vf.w + v2.w };
    float s = x[0] + x[1] + x[2] + x[3];
    float q = x[0]*x[0] + x[1]*x[1] + x[2]*x[2] + x[3]*x[3];
    for (int m = 32; m; m >>= 1) { s += __shfl_xor(s, m); q += __shfl_xor(q, m); }
    if ((t & 63) == 0) { reds[t >> 6] = s; reds[4 + (t >> 6)] = q; }
    __syncthreads();
    s = reds[0] + reds[1] + reds[2] + reds[3];
    q = reds[4] + reds[5] + reds[6] + reds[7];
    const float mean = s * (1.f / Dd);
    const float rstd = rsqrtf(q * (1.f / Dd) - mean * mean + 1e-5f);
    float y[4];
    #pragma unroll
    for (int j = 0; j < 4; ++j) {
        const int c = t * 4 + j;
        y[j] = (x[j] - mean) * rstd * g3[c] + b3[c];
    }
    ushort4 hy; hy.x = f2b(y[0]); hy.y = f2b(y[1]); hy.z = f2b(y[2]); hy.w = f2b(y[3]);
    *(ushort4*)(x3k + (size_t)r * Dd + t * 4) = hy;
    float q2 = y[0]*y[0] + y[1]*y[1] + y[2]*y[2] + y[3]*y[3];
    for (int m = 32; m; m >>= 1) q2 += __shfl_xor(q2, m);
    if ((t & 63) == 0) reds[8 + (t >> 6)] = q2;
    __syncthreads();
    if (k + 1 < Kk) {
        q2 = reds[8] + reds[9] + reds[10] + reds[11];
        const float sc = rsqrtf(q2 * (1.f / Dd) + 1e-8f);
        ushort4 hm; hm.x = f2b(y[0]*sc); hm.y = f2b(y[1]*sc); hm.z = f2b(y[2]*sc); hm.w = f2b(y[3]*sc);
        *(ushort4*)(merged + (size_t)r * (2 * Dd) + t * 4) = hm;
        const ushort4 ev = *(const ushort4*)(remb + (size_t)(b * Ss + k + 2 + i) * Dd + t * 4);
        *(ushort4*)(merged + (size_t)r * (2 * Dd) + Dd + t * 4) = ev;
    }
}

__global__ __launch_bounds__(256)
void gather_rms_merged(const int* __restrict__ xi, const float* __restrict__ table,
                       ushort* __restrict__ remb, ushort* __restrict__ merged) {
    __shared__ float reds[4];
    const int row = blockIdx.x;
    const int t = threadIdx.x;
    const int idx = xi[row];
    const float4 xv = *(const float4*)(table + (size_t)idx * Dd + t * 4);
    float q = xv.x*xv.x + xv.y*xv.y + xv.z*xv.z + xv.w*xv.w;
    for (int m = 32; m; m >>= 1) q += __shfl_xor(q, m);
    if ((t & 63) == 0) reds[t >> 6] = q;
    __syncthreads();
    q = reds[0] + reds[1] + reds[2] + reds[3];
    const float sc = rsqrtf(q * (1.f / Dd) + 1e-8f);
    ushort4 h;
    h.x = f2b(xv.x * sc); h.y = f2b(xv.y * sc); h.z = f2b(xv.z * sc); h.w = f2b(xv.w * sc);
    *(ushort4*)(remb + (size_t)row * Dd + t * 4) = h;
    const int b = row / Ss, s2 = row - b * Ss;
    if (s2 < Ii)
        *(ushort4*)(merged + (size_t)(b * Ii + s2) * (2 * Dd) + t * 4) = h;
    if (s2 >= 1 && s2 <= Ii)
        *(ushort4*)(merged + (size_t)(b * Ii + s2 - 1) * (2 * Dd) + Dd + t * 4) = h;
}

// ---------------- fallback f32-weight GEMM (round-1, proven) ----------------

__device__ inline bf16x8_t ld_frag(const ushort* p) {
    union { u64 l[2]; bf16x8_t s; } u;
    u.l[0] = *(const u64*)p;
    u.l[1] = *(const u64*)(p + 4);
    return u.s;
}

#define LDST 40

template<int KDIM, bool RELU, bool UNEMBED>
__global__ __launch_bounds__(256)
void gemm64(const ushort* __restrict__ A, const float* __restrict__ Wt,
            const float* __restrict__ bias, float* __restrict__ Cf,
            ushort* __restrict__ Cb, int Mrows, int N) {
    __shared__ ushort As[64 * LDST];
    __shared__ ushort Ws[64 * LDST];
    const int t    = threadIdx.x;
    const int tm0  = blockIdx.x * 64;
    const int tn0  = blockIdx.y * 64;
    const int lr   = t >> 2;
    const int lc   = (t & 3) * 8;
    const int wid  = t >> 6;
    const int lane = t & 63;
    const int wr   = (wid >> 1) * 32;
    const int wc   = (wid & 1) * 32;
    f32x4_t acc[2][2] = {};
    const bool avalid = (tm0 + lr) < Mrows;
    const ushort* Ap = A  + (size_t)(tm0 + lr) * KDIM + lc;
    const float*  Wp = Wt + (size_t)(tn0 + lr) * KDIM + lc;
    const int aoff = lr * LDST + lc;

    for (int k0 = 0; k0 < KDIM; k0 += 32) {
        union { uint4 qv; u64 l[2]; } av;
        av.qv = make_uint4(0u, 0u, 0u, 0u);
        if (avalid) av.qv = *(const uint4*)(Ap + k0);
        const float4 w0 = *(const float4*)(Wp + k0);
        const float4 w1 = *(const float4*)(Wp + k0 + 4);
        union { ushort us[8]; u64 l[2]; } wb;
        wb.us[0] = f2b(w0.x); wb.us[1] = f2b(w0.y); wb.us[2] = f2b(w0.z); wb.us[3] = f2b(w0.w);
        wb.us[4] = f2b(w1.x); wb.us[5] = f2b(w1.y); wb.us[6] = f2b(w1.z); wb.us[7] = f2b(w1.w);
        __syncthreads();
        *(u64*)&As[aoff]     = av.l[0];
        *(u64*)&As[aoff + 4] = av.l[1];
        *(u64*)&Ws[aoff]     = wb.l[0];
        *(u64*)&Ws[aoff + 4] = wb.l[1];
        __syncthreads();

        const ushort* ab = &As[(wr + (lane & 15)) * LDST + (lane >> 4) * 8];
        const ushort* bb = &Ws[(wc + (lane & 15)) * LDST + (lane >> 4) * 8];
        const bf16x8_t fa0 = ld_frag(ab);
        const bf16x8_t fa1 = ld_frag(ab + 16 * LDST);
        const bf16x8_t fb0 = ld_frag(bb);
        const bf16x8_t fb1 = ld_frag(bb + 16 * LDST);
        acc[0][0] = __builtin_amdgcn_mfma_f32_16x16x32_bf16(fa0, fb0, acc[0][0], 0, 0, 0);
        acc[0][1] = __builtin_amdgcn_mfma_f32_16x16x32_bf16(fa0, fb1, acc[0][1], 0, 0, 0);
        acc[1][0] = __builtin_amdgcn_mfma_f32_16x16x32_bf16(fa1, fb0, acc[1][0], 0, 0, 0);
        acc[1][1] = __builtin_amdgcn_mfma_f32_16x16x32_bf16(fa1, fb1, acc[1][1], 0, 0, 0);
    }

    const int rb = (lane >> 4) * 4;
    const int cl = lane & 15;
    for (int m = 0; m < 2; ++m)
        for (int n = 0; n < 2; ++n)
            for (int i = 0; i < 4; ++i) {
                const int r = tm0 + wr + m * 16 + rb + i;
                const int c = tn0 + wc + n * 16 + cl;
                if (r < Mrows) {
                    float v = acc[m][n][i];
                    if (bias) v += bias[c];
                    if (RELU) v = fmaxf(v, 0.f);
                    if (UNEMBED) {
                        const int kk  = r / Mm;
                        const int rem = r - kk * Mm;
                        Cf[(size_t)(rem * Kk + kk) * Vv + c] = v;
                    } else {
                        if (Cf) Cf[(size_t)r * N + c] = v;
                        if (Cb) Cb[(size_t)r * N + c] = f2b(v);
                    }
                }
            }
}

__global__ __launch_bounds__(256)
void ln_kernel(const float* __restrict__ a, const float* __restrict__ rsd,
               const float* __restrict__ g, const float* __restrict__ bb,
               float* __restrict__ outf, ushort* __restrict__ outb) {
    __shared__ float reds[8];
    const int row = blockIdx.x;
    const int t = threadIdx.x;
    const float4 xa = *(const float4*)(a   + (size_t)row * Dd + t * 4);
    const float4 xr = *(const float4*)(rsd + (size_t)row * Dd + t * 4);
    float x[4] = { xa.x + xr.x, xa.y + xr.y, xa.z + xr.z, xa.w + xr.w };
    float s = x[0] + x[1] + x[2] + x[3];
    float q = x[0]*x[0] + x[1]*x[1] + x[2]*x[2] + x[3]*x[3];
    for (int msk = 32; msk; msk >>= 1) { s += __shfl_xor(s, msk); q += __shfl_xor(q, msk); }
    if ((t & 63) == 0) { reds[t >> 6] = s; reds[4 + (t >> 6)] = q; }
    __syncthreads();
    s = reds[0] + reds[1] + reds[2] + reds[3];
    q = reds[4] + reds[5] + reds[6] + reds[7];
    const float m    = s * (1.f / Dd);
    const float var  = q * (1.f / Dd) - m * m;
    const float rstd = rsqrtf(var + 1e-5f);
    float y[4];
    #pragma unroll
    for (int j = 0; j < 4; ++j) {
        const int c = t * 4 + j;
        y[j] = (x[j] - m) * rstd * g[c] + bb[c];
    }
    if (outf) *(float4*)(outf + (size_t)row * Dd + t * 4) = make_float4(y[0], y[1], y[2], y[3]);
    if (outb) {
        ushort4 h; h.x = f2b(y[0]); h.y = f2b(y[1]); h.z = f2b(y[2]); h.w = f2b(y[3]);
        *(ushort4*)(outb + (size_t)row * Dd + t * 4) = h;
    }
}

__global__ __launch_bounds__(256)
void build_merged(const float* __restrict__ h, const ushort* __restrict__ remb,
                  ushort* __restrict__ merged, int k) {
    __shared__ float reds[4];
    const int r = blockIdx.x;
    const int t = threadIdx.x;
    const int b = r / Ii;
    const int i = r - b * Ii;
    if (k == 0) {
        const ushort4 hv = *(const ushort4*)(remb + (size_t)(b * Ss + i) * Dd + t * 4);
        *(ushort4*)(merged + (size_t)r * (2 * Dd) + t * 4) = hv;
    } else {
        const float4 xv = *(const float4*)(h + (size_t)r * Dd + t * 4);
        float q = xv.x*xv.x + xv.y*xv.y + xv.z*xv.z + xv.w*xv.w;
        for (int msk = 32; msk; msk >>= 1) q += __shfl_xor(q, msk);
        if ((t & 63) == 0) reds[t >> 6] = q;
        __syncthreads();
        q = reds[0] + reds[1] + reds[2] + reds[3];
        const float sc = rsqrtf(q * (1.f / Dd) + 1e-8f);
        ushort4 hv;
        hv.x = f2b(xv.x * sc); hv.y = f2b(xv.y * sc); hv.z = f2b(xv.z * sc); hv.w = f2b(xv.w * sc);
        *(ushort4*)(merged + (size_t)r * (2 * Dd) + t * 4) = hv;
    }
    const ushort4 ev = *(const ushort4*)(remb + (size_t)(b * Ss + k + 1 + i) * Dd + t * 4);
    *(ushort4*)(merged + (size_t)r * (2 * Dd) + Dd + t * 4) = ev;
}

__global__ __launch_bounds__(256)
void gather_rms(const int* __restrict__ xi, const float* __restrict__ table,
                ushort* __restrict__ remb) {
    __shared__ float reds[4];
    const int row = blockIdx.x;
    const int t = threadIdx.x;
    const int idx = xi[row];
    const float4 xv = *(const float4*)(table + (size_t)idx * Dd + t * 4);
    float q = xv.x*xv.x + xv.y*xv.y + xv.z*xv.z + xv.w*xv.w;
    for (int msk = 32; msk; msk >>= 1) q += __shfl_xor(q, msk);
    if ((t & 63) == 0) reds[t >> 6] = q;
    __syncthreads();
    q = reds[0] + reds[1] + reds[2] + reds[3];
    const float sc = rsqrtf(q * (1.f / Dd) + 1e-8f);
    ushort4 h;
    h.x = f2b(xv.x * sc); h.y = f2b(xv.y * sc); h.z = f2b(xv.z * sc); h.w = f2b(xv.w * sc);
    *(ushort4*)(remb + (size_t)row * Dd + t * 4) = h;
}

// ---------------- launcher ----------------

extern "C" void kernel_launch(void* const* d_in, const int* in_sizes, int n_in,
                              void* d_out, int out_size, void* d_ws, size_t ws_size,
                              hipStream_t stream) {
    const int*   x      = (const int*)  d_in[0];
    const float* table  = (const float*)d_in[1];
    const float* unemb  = (const float*)d_in[2];
    const float* proj_w = (const float*)d_in[3];
    const float* proj_b = (const float*)d_in[4];
    const float* sa_wv  = (const float*)d_in[5];
    const float* sa_bv  = (const float*)d_in[6];
    const float* sa_wo  = (const float*)d_in[7];
    const float* sa_bo  = (const float*)d_in[8];
    const float* ln1_g  = (const float*)d_in[9];
    const float* ln1_b  = (const float*)d_in[10];
    const float* ca_wv  = (const float*)d_in[11];
    const float* ca_bv  = (const float*)d_in[12];
    const float* ca_wo  = (const float*)d_in[13];
    const float* ca_bo  = (const float*)d_in[14];
    const float* ln2_g  = (const float*)d_in[15];
    const float* ln2_b  = (const float*)d_in[16];
    const float* ff_w1  = (const float*)d_in[17];
    const float* ff_b1  = (const float*)d_in[18];
    const float* ff_w2  = (const float*)d_in[19];
    const float* ff_b2  = (const float*)d_in[20];
    const float* ln3_g  = (const float*)d_in[21];
    const float* ln3_b  = (const float*)d_in[22];
    float* out = (float*)d_out;

    char* ws = (char*)d_ws;
    size_t off = 0;
    auto alloc = [&](size_t bytes) -> void* {
        void* p = ws + off;
        off = (off + bytes + 255) & ~(size_t)255;
        return p;
    };

    const size_t NEED = 262100000;

    if (ws_size >= NEED) {
        ushort* wU  = (ushort*)alloc((size_t)Vv * Dd * 2);
        ushort* wP  = (ushort*)alloc((size_t)Kk * Dd * 2 * Dd * 2);
        ushort* wV  = (ushort*)alloc((size_t)Kk * 2 * Dd * Dd * 2);
        ushort* wOs = (ushort*)alloc((size_t)Kk * Dd * Dd * 2);
        ushort* wOc = (ushort*)alloc((size_t)Kk * Dd * Dd * 2);
        ushort* wF1 = (ushort*)alloc((size_t)Kk * Ff * Dd * 2);
        ushort* wF2 = (ushort*)alloc((size_t)Kk * Dd * Ff * 2);
        float*  bV  = (float*) alloc((size_t)Kk * 2 * Dd * 4);
        ushort* remb   = (ushort*)alloc((size_t)Bz * Ss * Dd * 2);
        ushort* merged = (ushort*)alloc((size_t)Mp * 2 * Dd * 2);
        float*  xpf    = (float*) alloc((size_t)Mp * Dd * 4);
        ushort* xpb    = (ushort*)alloc((size_t)Mp * Dd * 2);
        ushort* tb     = (ushort*)alloc((size_t)Mp * 2 * Dd * 2);
        float*  sfa    = (float*) alloc((size_t)Mp * Dd * 4);
        float*  sfc    = (float*) alloc((size_t)Mp * Dd * 4);
        float*  x2f    = (float*) alloc((size_t)Mp * Dd * 4);
        ushort* x2b    = (ushort*)alloc((size_t)Mp * Dd * 2);
        ushort* x3all  = (ushort*)alloc((size_t)Mx * Dd * 2);

        const long pP  = (long)Dd * 2 * Dd;   // 2M elems/k
        const long pDD = (long)Dd * Dd;       // 1M
        const long pV  = 2 * pDD;
        const long pF  = (long)Ff * Dd;       // 2M

        // --- single fused convert launch (one task table; chunk = 4096 elems) ---
        CvTab tab; int cum = 0; tab.n = 0;
        auto addTask = [&](const float* s, ushort* d, long elems) {
            tab.src[tab.n] = (u64)s; tab.dst[tab.n] = (u64)d;
            tab.start[tab.n] = cum; cum += (int)(elems / 4096); tab.n++;
        };
        addTask(unemb,  wU,  (long)Vv * Dd);           // 8000 chunks
        addTask(proj_w, wP,  (long)Kk * pP);           // 4096
        addTask(sa_wo,  wOs, (long)Kk * pDD);          // 2048
        addTask(ca_wo,  wOc, (long)Kk * pDD);          // 2048
        addTask(ff_w1,  wF1, (long)Kk * pF);           // 4096
        addTask(ff_w2,  wF2, (long)Kk * pF);           // 4096
        for (int k = 0; k < Kk; ++k) {                 // wV interleave [k][sa;ca]
            addTask(sa_wv + (size_t)k * pDD, wV + (size_t)k * pV, pDD);        // 256 ea
            addTask(ca_wv + (size_t)k * pDD, wV + (size_t)k * pV + pDD, pDD);  // 256 ea
        }
        tab.start[tab.n] = cum;

        gather_rms_merged<<<Bz * Ss, 256, 0, stream>>>(x, table, remb, merged);
        convert_all<<<cum, 256, 0, stream>>>(tab);
        copyf_k<<<32, 256, 0, stream>>>(sa_bv, bV, (long)Kk * Dd, Dd, 2 * Dd, 0);
        copyf_k<<<32, 256, 0, stream>>>(ca_bv, bV, (long)Kk * Dd, Dd, 2 * Dd, Dd);

        for (int k = 0; k < Kk; ++k) {
            gemm3<32, 64, 64, 256, 3, false, false><<<dim3(Mp/32, Dd/64, 1), 256, 0, stream>>>(
                merged, merged, 2 * Dd, wP + (size_t)k * pP, wP + (size_t)k * pP,
                proj_b + k * Dd, proj_b + k * Dd, xpf, xpf, xpb, xpb, Mm, Dd, 2 * Dd);
            gemm3<32, 64, 64, 256, 3, false, false><<<dim3(Mp/32, 2*Dd/64, 1), 256, 0, stream>>>(
                xpb, xpb, Dd, wV + (size_t)k * pV, wV + (size_t)k * pV,
                bV + (size_t)k * 2 * Dd, bV + (size_t)k * 2 * Dd,
                nullptr, nullptr, tb, tb, Mm, 2 * Dd, Dd);
            gemm3<32, 64, 64, 256, 3, false, false><<<dim3(Mp/32, Dd/64, 2), 256, 0, stream>>>(
                tb, tb + Dd, 2 * Dd, wOs + (size_t)k * pDD, wOc + (size_t)k * pDD,
                sa_bo + k * Dd, ca_bo + k * Dd, sfa, sfc, nullptr, nullptr, Mm, Dd, Dd);
            ln12_kernel<<<Mm, 256, 0, stream>>>(sfa, xpf, sfc,
                ln1_g + k * Dd, ln1_b + k * Dd, ln2_g + k * Dd, ln2_b + k * Dd, x2f, x2b);
            gemm3<32, 64, 64, 256, 3, true, false><<<dim3(Mp/32, Ff/64, 1), 256, 0, stream>>>(
                x2b, x2b, Dd, wF1 + (size_t)k * pF, wF1 + (size_t)k * pF,
                ff_b1 + k * Ff, ff_b1 + k * Ff, nullptr, nullptr, tb, tb, Mm, Ff, Dd);
            gemm3<32, 64, 64, 256, 3, false, false><<<dim3(Mp/32, Dd/64, 1), 256, 0, stream>>>(
                tb, tb, Ff, wF2 + (size_t)k * pF, wF2 + (size_t)k * pF,
                ff_b2 + k * Dd, ff_b2 + k * Dd, sfa, sfa, nullptr, nullptr, Mm, Dd, Ff);
            ln3m_kernel<<<Mm, 256, 0, stream>>>(sfa, x2f, ln3_g + k * Dd, ln3_b + k * Dd,
                remb, x3all + (size_t)k * Mm * Dd, merged, k);
        }

        // unembed: 32x32x16 MFMA, 256x256/BK=64, PF=2 counted-vmcnt + nt C-store
        gemm32<<<dim3(Mx/256, Vv/256, 1), 512, 0, stream>>>(x3all, wU, out, Mu, Dd);
        return;
    }

    // ---------------- fallback: round-1 proven f32-weight path ----------------
    ushort* remb   = (ushort*)alloc((size_t)Bz * Ss * Dd * 2);
    ushort* merged = (ushort*)alloc((size_t)Mm * 2 * Dd * 2);
    float*  xpf    = (float*) alloc((size_t)Mm * Dd * 4);
    ushort* xpb    = (ushort*)alloc((size_t)Mm * Dd * 2);
    ushort* tb     = (ushort*)alloc((size_t)Mm * Ff * 2);
    float*  sf     = (float*) alloc((size_t)Mm * Dd * 4);
    float*  x1f    = (float*) alloc((size_t)Mm * Dd * 4);
    float*  x2f    = (float*) alloc((size_t)Mm * Dd * 4);
    ushort* x2b    = (ushort*)alloc((size_t)Mm * Dd * 2);
    float*  hbuf   = (float*) alloc((size_t)Mm * Dd * 4);
    ushort* x3all  = (ushort*)alloc((size_t)Kk * Mm * Dd * 2);

    gather_rms<<<Bz * Ss, 256, 0, stream>>>(x, table, remb);

    const dim3 gD((Mm + 63) / 64, Dd / 64);
    const dim3 gF((Mm + 63) / 64, Ff / 64);
    for (int k = 0; k < Kk; ++k) {
        build_merged<<<Mm, 256, 0, stream>>>(hbuf, remb, merged, k);
        gemm64<2 * Dd, false, false><<<gD, 256, 0, stream>>>(
            merged, proj_w + (size_t)k * Dd * 2 * Dd, proj_b + k * Dd, xpf, xpb, Mm, Dd);
        gemm64<Dd, false, false><<<gD, 256, 0, stream>>>(
            xpb, sa_wv + (size_t)k * Dd * Dd, sa_bv + k * Dd, nullptr, tb, Mm, Dd);
        gemm64<Dd, false, false><<<gD, 256, 0, stream>>>(
            tb, sa_wo + (size_t)k * Dd * Dd, sa_bo + k * Dd, sf, nullptr, Mm, Dd);
        ln_kernel<<<Mm, 256, 0, stream>>>(sf, xpf, ln1_g + k * Dd, ln1_b + k * Dd, x1f, nullptr);
        gemm64<Dd, false, false><<<gD, 256, 0, stream>>>(
            xpb, ca_wv + (size_t)k * Dd * Dd, ca_bv + k * Dd, nullptr, tb, Mm, Dd);
        gemm64<Dd, false, false><<<gD, 256, 0, stream>>>(
            tb, ca_wo + (size_t)k * Dd * Dd, ca_bo + k * Dd, sf, nullptr, Mm, Dd);
        ln_kernel<<<Mm, 256, 0, stream>>>(sf, x1f, ln2_g + k * Dd, ln2_b + k * Dd, x2f, x2b);
        gemm64<Dd, true, false><<<gF, 256, 0, stream>>>(
            x2b, ff_w1 + (size_t)k * Ff * Dd, ff_b1 + k * Ff, nullptr, tb, Mm, Ff);
        gemm64<Ff, false, false><<<gD, 256, 0, stream>>>(
            tb, ff_w2 + (size_t)k * Dd * Ff, ff_b2 + k * Dd, sf, nullptr, Mm, Dd);
        ln_kernel<<<Mm, 256, 0, stream>>>(sf, x2f, ln3_g + k * Dd, ln3_b + k * Dd,
                                          hbuf, x3all + (size_t)k * Mm * Dd);
    }

    const dim3 gU((Kk * Mm) / 64, Vv / 64);
    gemm64<Dd, false, true><<<gU, 256, 0, stream>>>(x3all, unemb, nullptr, out, nullptr, Kk * Mm, Vv);
}

// Round 15
// 962.107 us; speedup vs baseline: 1.0792x; 1.0792x over previous
//
#include <hip/hip_runtime.h>
#include <hip/hip_bf16.h>

#define Dd 1024
#define Ss 256
#define Bz 2
#define Kk 8
#define Vv 32000
#define Ff 2048
#define Ii 248
#define Mm (Bz*Ii)    // 496
#define Mp 512        // padded activation rows
#define Mu (Kk*Mm)    // 3968
#define Mx 4096       // unembed M padded to 256-multiple

typedef __attribute__((ext_vector_type(8))) short bf16x8_t;
typedef __attribute__((ext_vector_type(4))) float f32x4_t;
typedef __attribute__((ext_vector_type(16))) float f32x16_t;
typedef unsigned long long u64;

__device__ inline ushort f2b(float f) {
    union { float f; unsigned u; } v; v.f = f;
    unsigned u = v.u;
    unsigned r = (u + 0x7fffu + ((u >> 16) & 1u)) >> 16;  // RNE
    return (ushort)r;
}

__device__ inline void gload16(const void* g, void* l) {
    __builtin_amdgcn_global_load_lds((const __attribute__((address_space(1))) void*)g,
                                     (__attribute__((address_space(3))) void*)l, 16, 0, 0);
}

template<int N> __device__ inline void wait_vmcnt() {
    asm volatile("s_waitcnt vmcnt(%0)" :: "n"(N) : "memory");
}
__device__ inline void bar() {
    asm volatile("" ::: "memory");
    __builtin_amdgcn_s_barrier();
    asm volatile("" ::: "memory");
}

// XOR swizzle on 16B slots within a row (both-sides-or-neither, rule #21).
template<int BK>
__device__ inline int swz(int s, int r) {
    if constexpr (BK == 64) return s ^ (r & 7);        // 8 slots/row
    else                    return s ^ ((r >> 1) & 3); // BK=32: 4 slots/row
}

// =============== unembed GEMM: 32x32x16 MFMA (R11 best: 256x256/BK=64 + nt store) ===============
__global__ __launch_bounds__(512, 2)
void gemm32(const ushort* __restrict__ A, const ushort* __restrict__ W,
            float* __restrict__ Cf, int Mrows, int KDIM) {
    constexpr int BM = 256, BN = 256, BK = 64, TH = 512, PF = 2;
    constexpr int TILE = (BM + BN) * BK;        // 64 KB
    constexpr int ABYTES = BM * BK * 2;
    constexpr int L = (BM + BN) * BK * 2 / (TH * 16);  // 8
    __shared__ __align__(16) ushort sm[PF * TILE];     // 128 KB

    int bx = blockIdx.x, by = blockIdx.y;
    {   // bijective XCD-aware swizzle (m204)
        const int nwg  = gridDim.x * gridDim.y;
        const int orig = by * gridDim.x + bx;
        const int q = nwg >> 3, r = nwg & 7;
        const int xcd = orig & 7, lin = orig >> 3;
        const int wg = (xcd < r ? xcd * (q + 1) : r * (q + 1) + (xcd - r) * q) + lin;
        bx = wg % gridDim.x; by = wg / gridDim.x;
    }
    const int t    = threadIdx.x;
    const int lane = t & 63;
    const int w    = t >> 6;
    const int wr   = (w >> 2) * 128;            // wave grid 2 x 4
    const int wc   = (w & 3) * 64;
    const int tm0  = bx * BM, tn0 = by * BN;

    const ushort* Abase = A + (size_t)tm0 * KDIM;
    const ushort* Wbase = W + (size_t)tn0 * KDIM;

    const ushort* gp[L]; int lo[L];
    #pragma unroll
    for (int j = 0; j < L; ++j) {
        const int i = (t + j * TH) * 16;
        int r, s; const ushort* base;
        if (i < ABYTES) { r = i / (BK * 2); s = (i >> 4) % (BK / 8); base = Abase; }
        else { const int i2 = i - ABYTES; r = i2 / (BK * 2); s = (i2 >> 4) % (BK / 8); base = Wbase; }
        gp[j] = base + (size_t)r * KDIM + (size_t)swz<BK>(s, r) * 8;
        lo[j] = i / 2;
    }
    auto stage = [&](int buf) {
        #pragma unroll
        for (int j = 0; j < L; ++j) gload16(gp[j], &sm[buf * TILE + lo[j]]);
        #pragma unroll
        for (int j = 0; j < L; ++j) gp[j] += BK;
    };

    const int rl = lane & 31, hk = lane >> 5;
    int aoff[4][4], boff[2][4];
    #pragma unroll
    for (int m = 0; m < 4; ++m)
        #pragma unroll
        for (int ks = 0; ks < 4; ++ks) {
            const int r = wr + m * 32 + rl;
            aoff[m][ks] = r * BK + swz<BK>(ks * 2 + hk, r) * 8;
        }
    #pragma unroll
    for (int n = 0; n < 2; ++n)
        #pragma unroll
        for (int ks = 0; ks < 4; ++ks) {
            const int r = wc + n * 32 + rl;
            boff[n][ks] = BM * BK + r * BK + swz<BK>(ks * 2 + hk, r) * 8;
        }

    f32x16_t acc[4][2] = {};
    const int NT = KDIM / BK;                   // 16

    stage(0); stage(1);
    int buf = 0;
    for (int kt = 0; kt < NT; ++kt) {
        const int remT = NT - 1 - kt;
        if (remT >= 1) wait_vmcnt<L>(); else wait_vmcnt<0>();
        bar();

        const ushort* smb = &sm[buf * TILE];
        #pragma unroll
        for (int ks = 0; ks < 4; ++ks) {
            bf16x8_t af[4], bf[2];
            #pragma unroll
            for (int m = 0; m < 4; ++m) af[m] = *(const bf16x8_t*)&smb[aoff[m][ks]];
            #pragma unroll
            for (int n = 0; n < 2; ++n) bf[n] = *(const bf16x8_t*)&smb[boff[n][ks]];
            #pragma unroll
            for (int m = 0; m < 4; ++m)
                #pragma unroll
                for (int n = 0; n < 2; ++n)
                    acc[m][n] = __builtin_amdgcn_mfma_f32_32x32x16_bf16(af[m], bf[n], acc[m][n], 0, 0, 0);
        }
        bar();
        if (kt + PF < NT) stage(buf);
        buf ^= 1;
    }

    // C/D: col=lane&31, row=(reg&3)+8*(reg>>2)+4*(lane>>5)  [m74/m101]
    const int cl = lane & 31;
    #pragma unroll
    for (int m = 0; m < 4; ++m)
        #pragma unroll
        for (int n = 0; n < 2; ++n)
            #pragma unroll
            for (int reg = 0; reg < 16; ++reg) {
                const int row = (reg & 3) + 8 * (reg >> 2) + 4 * hk;
                const int r = tm0 + wr + m * 32 + row;
                const int c = tn0 + wc + n * 32 + cl;
                if (r < Mrows) {
                    const int kk  = r / Mm;
                    const int rem = r - kk * Mm;
                    __builtin_nontemporal_store(acc[m][n][reg],
                        &Cf[(size_t)(rem * Kk + kk) * Vv + c]);
                }
            }
}

// ---------------- counted-vmcnt PF-deep bf16 GEMM (chain, proven R8/R11) ----------------
template<int BM, int BN, int BK, int TH, int PF, bool RELU, bool UNEMBED>
__global__ __launch_bounds__(TH, 2)
void gemm3(const ushort* __restrict__ A0, const ushort* __restrict__ A1, int lda,
           const ushort* __restrict__ W0, const ushort* __restrict__ W1,
           const float* __restrict__ b0, const float* __restrict__ b1,
           float* __restrict__ Cf0, float* __restrict__ Cf1,
           ushort* __restrict__ Cb0, ushort* __restrict__ Cb1,
           int Mrows, int N, int KDIM) {
    constexpr int NW = TH / 64;
    constexpr int WN = NW / 2;
    constexpr int MR = (BM / 2) / 16;
    constexpr int NR = (BN / WN) / 16;
    constexpr int TILE = (BM + BN) * BK;
    constexpr int ABYTES = BM * BK * 2;
    constexpr int TOT = (BM + BN) * BK * 2;
    constexpr int L = TOT / (TH * 16);
    constexpr int KS = BK / 32;

    __shared__ __align__(16) ushort sm[PF * TILE];

    const ushort* A = A0; const ushort* W = W0; const float* bias = b0;
    float* Cf = Cf0; ushort* Cb = Cb0;
    if (blockIdx.z) { A = A1; W = W1; bias = b1; Cf = Cf1; Cb = Cb1; }

    const int t    = threadIdx.x;
    const int tm0  = blockIdx.x * BM;
    const int tn0  = blockIdx.y * BN;
    const int lane = t & 63;
    const int w    = t >> 6;
    const int wr   = (w / WN) * (BM / 2);
    const int wc   = (w % WN) * (BN / WN);

    const ushort* Abase = A + (size_t)tm0 * lda;
    const ushort* Wbase = W + (size_t)tn0 * KDIM;

    const ushort* gp[L];
    int lo[L];
    #pragma unroll
    for (int j = 0; j < L; ++j) {
        const int i = (t + j * TH) * 16;
        int r, s; const ushort* base; int ld;
        if (i < ABYTES) { r = i / (BK * 2); s = (i >> 4) % (BK / 8); base = Abase; ld = lda; }
        else { const int i2 = i - ABYTES; r = i2 / (BK * 2); s = (i2 >> 4) % (BK / 8); base = Wbase; ld = KDIM; }
        gp[j] = base + (size_t)r * ld + swz<BK>(s, r) * 8;
        lo[j] = i / 2;
    }
    auto stage = [&](int buf) {
        #pragma unroll
        for (int j = 0; j < L; ++j) gload16(gp[j], &sm[buf * TILE + lo[j]]);
        #pragma unroll
        for (int j = 0; j < L; ++j) gp[j] += BK;
    };

    const int h = lane >> 4, rl = lane & 15;
    int aoff[MR][KS], boff[NR][KS];
    #pragma unroll
    for (int m = 0; m < MR; ++m)
        #pragma unroll
        for (int kk = 0; kk < KS; ++kk) {
            const int r = wr + m * 16 + rl;
            aoff[m][kk] = r * BK + swz<BK>(kk * 4 + h, r) * 8;
        }
    #pragma unroll
    for (int n = 0; n < NR; ++n)
        #pragma unroll
        for (int kk = 0; kk < KS; ++kk) {
            const int r = wc + n * 16 + rl;
            boff[n][kk] = BM * BK + r * BK + swz<BK>(kk * 4 + h, r) * 8;
        }

    f32x4_t acc[MR][NR] = {};

    const int NT = KDIM / BK;
    #pragma unroll
    for (int p = 0; p < PF; ++p) stage(p);

    int buf = 0;
    for (int kt = 0; kt < NT; ++kt) {
        const int remT = NT - 1 - kt;
        const int wv = remT < PF - 1 ? remT : PF - 1;
        switch (wv) {
            case 0:  wait_vmcnt<0>();     break;
            case 1:  wait_vmcnt<1 * L>(); break;
            case 2:  wait_vmcnt<2 * L>(); break;
            default: wait_vmcnt<3 * L>(); break;
        }
        bar();

        const ushort* smb = &sm[buf * TILE];
        #pragma unroll
        for (int kk = 0; kk < KS; ++kk) {
            bf16x8_t af[MR], bf[NR];
            #pragma unroll
            for (int m = 0; m < MR; ++m) af[m] = *(const bf16x8_t*)&smb[aoff[m][kk]];
            #pragma unroll
            for (int n = 0; n < NR; ++n) bf[n] = *(const bf16x8_t*)&smb[boff[n][kk]];
            #pragma unroll
            for (int m = 0; m < MR; ++m)
                #pragma unroll
                for (int n = 0; n < NR; ++n)
                    acc[m][n] = __builtin_amdgcn_mfma_f32_16x16x32_bf16(af[m], bf[n], acc[m][n], 0, 0, 0);
        }
        bar();
        if (kt + PF < NT) stage(buf);
        buf = (buf + 1 == PF) ? 0 : buf + 1;
    }

    const int rb = (lane >> 4) * 4;
    const int cl = lane & 15;
    #pragma unroll
    for (int m = 0; m < MR; ++m)
        #pragma unroll
        for (int n = 0; n < NR; ++n)
            #pragma unroll
            for (int i = 0; i < 4; ++i) {
                const int r = tm0 + wr + m * 16 + rb + i;
                const int c = tn0 + wc + n * 16 + cl;
                if (r < Mrows) {
                    float v = acc[m][n][i];
                    if (bias) v += bias[c];
                    if (RELU) v = fmaxf(v, 0.f);
                    if (UNEMBED) {
                        const int kk  = r / Mm;
                        const int rem = r - kk * Mm;
                        Cf[(size_t)(rem * Kk + kk) * Vv + c] = v;
                    } else {
                        if (Cf) Cf[(size_t)r * N + c] = v;
                        if (Cb) Cb[(size_t)r * N + c] = f2b(v);
                    }
                }
            }
}

// ---------------- weight conversion (coalesced grid-stride, proven R11) ----------------
__global__ __launch_bounds__(256)
void convert_k(const float* __restrict__ src, ushort* __restrict__ dst,
               long n, long perK, long dstPerK, long dstOff) {
    long i = ((long)blockIdx.x * 256 + threadIdx.x) * 4;
    const long stride = (long)gridDim.x * 1024;
    for (; i < n; i += stride) {
        const float4 v = *(const float4*)(src + i);
        const long k = i / perK, rem = i - k * perK;
        ushort4 hh; hh.x = f2b(v.x); hh.y = f2b(v.y); hh.z = f2b(v.z); hh.w = f2b(v.w);
        *(ushort4*)(dst + k * dstPerK + dstOff + rem) = hh;
    }
}

__global__ __launch_bounds__(256)
void copyf_k(const float* __restrict__ src, float* __restrict__ dst,
             long n, long perK, long dstPerK, long dstOff) {
    long i = (long)blockIdx.x * 256 + threadIdx.x;
    const long stride = (long)gridDim.x * 256;
    for (; i < n; i += stride) {
        const long k = i / perK, rem = i - k * perK;
        dst[k * dstPerK + dstOff + rem] = src[i];
    }
}

// ---------------- fused elementwise kernels ----------------

__global__ __launch_bounds__(256)
void ln12_kernel(const float* __restrict__ sa, const float* __restrict__ xp,
                 const float* __restrict__ ca,
                 const float* __restrict__ g1, const float* __restrict__ b1,
                 const float* __restrict__ g2, const float* __restrict__ b2,
                 float* __restrict__ x2f, ushort* __restrict__ x2b) {
    __shared__ float reds[16];
    const int row = blockIdx.x;
    const int t = threadIdx.x;
    const float4 va = *(const float4*)(sa + (size_t)row * Dd + t * 4);
    const float4 vp = *(const float4*)(xp + (size_t)row * Dd + t * 4);
    float x[4] = { va.x + vp.x, va.y + vp.y, va.z + vp.z, va.w + vp.w };
    float s = x[0] + x[1] + x[2] + x[3];
    float q = x[0]*x[0] + x[1]*x[1] + x[2]*x[2] + x[3]*x[3];
    for (int m = 32; m; m >>= 1) { s += __shfl_xor(s, m); q += __shfl_xor(q, m); }
    if ((t & 63) == 0) { reds[t >> 6] = s; reds[4 + (t >> 6)] = q; }
    __syncthreads();
    s = reds[0] + reds[1] + reds[2] + reds[3];
    q = reds[4] + reds[5] + reds[6] + reds[7];
    float mean = s * (1.f / Dd);
    float rstd = rsqrtf(q * (1.f / Dd) - mean * mean + 1e-5f);
    const float4 vc = *(const float4*)(ca + (size_t)row * Dd + t * 4);
    float y[4];
    #pragma unroll
    for (int j = 0; j < 4; ++j) {
        const int c = t * 4 + j;
        y[j] = (x[j] - mean) * rstd * g1[c] + b1[c] + ((const float*)&vc)[j];
    }
    s = y[0] + y[1] + y[2] + y[3];
    q = y[0]*y[0] + y[1]*y[1] + y[2]*y[2] + y[3]*y[3];
    for (int m = 32; m; m >>= 1) { s += __shfl_xor(s, m); q += __shfl_xor(q, m); }
    if ((t & 63) == 0) { reds[8 + (t >> 6)] = s; reds[12 + (t >> 6)] = q; }
    __syncthreads();
    s = reds[8] + reds[9] + reds[10] + reds[11];
    q = reds[12] + reds[13] + reds[14] + reds[15];
    mean = s * (1.f / Dd);
    rstd = rsqrtf(q * (1.f / Dd) - mean * mean + 1e-5f);
    float z[4]; ushort4 hb;
    #pragma unroll
    for (int j = 0; j < 4; ++j) {
        const int c = t * 4 + j;
        z[j] = (y[j] - mean) * rstd * g2[c] + b2[c];
    }
    hb.x = f2b(z[0]); hb.y = f2b(z[1]); hb.z = f2b(z[2]); hb.w = f2b(z[3]);
    *(float4*)(x2f + (size_t)row * Dd + t * 4) = make_float4(z[0], z[1], z[2], z[3]);
    *(ushort4*)(x2b + (size_t)row * Dd + t * 4) = hb;
}

__global__ __launch_bounds__(256)
void ln3m_kernel(const float* __restrict__ ff, const float* __restrict__ x2,
                 const float* __restrict__ g3, const float* __restrict__ b3,
                 const ushort* __restrict__ remb, ushort* __restrict__ x3k,
                 ushort* __restrict__ merged, int k) {
    __shared__ float reds[12];
    const int r = blockIdx.x;
    const int t = threadIdx.x;
    const int b = r / Ii, i = r - b * Ii;
    const float4 vf = *(const float4*)(ff + (size_t)r * Dd + t * 4);
    const float4 v2 = *(const float4*)(x2 + (size_t)r * Dd + t * 4);
    float x[4] = { vf.x + v2.x, vf.y + v2.y, vf.z + v2.z, vf.w + v2.w };
    float s = x[0] + x[1] + x[2] + x[3];
    float q = x[0]*x[0] + x[1]*x[1] + x[2]*x[2] + x[3]*x[3];
    for (int m = 32; m; m >>= 1) { s += __shfl_xor(s, m); q += __shfl_xor(q, m); }
    if ((t & 63) == 0) { reds[t >> 6] = s; reds[4 + (t >> 6)] = q; }
    __syncthreads();
    s = reds[0] + reds[1] + reds[2] + reds[3];
    q = reds[4] + reds[5] + reds[6] + reds[7];
    const float mean = s * (1.f / Dd);
    const float rstd = rsqrtf(q * (1.f / Dd) - mean * mean + 1e-5f);
    float y[4];
    #pragma unroll
    for (int j = 0; j < 4; ++j) {
        const int c = t * 4 + j;
        y[j] = (x[j] - mean) * rstd * g3[c] + b3[c];
    }
    ushort4 hy; hy.x = f2b(y[0]); hy.y = f2b(y[1]); hy.z = f2b(y[2]); hy.w = f2b(y[3]);
    *(ushort4*)(x3k + (size_t)r * Dd + t * 4) = hy;
    float q2 = y[0]*y[0] + y[1]*y[1] + y[2]*y[2] + y[3]*y[3];
    for (int m = 32; m; m >>= 1) q2 += __shfl_xor(q2, m);
    if ((t & 63) == 0) reds[8 + (t >> 6)] = q2;
    __syncthreads();
    if (k + 1 < Kk) {
        q2 = reds[8] + reds[9] + reds[10] + reds[11];
        const float sc = rsqrtf(q2 * (1.f / Dd) + 1e-8f);
        ushort4 hm; hm.x = f2b(y[0]*sc); hm.y = f2b(y[1]*sc); hm.z = f2b(y[2]*sc); hm.w = f2b(y[3]*sc);
        *(ushort4*)(merged + (size_t)r * (2 * Dd) + t * 4) = hm;
        const ushort4 ev = *(const ushort4*)(remb + (size_t)(b * Ss + k + 2 + i) * Dd + t * 4);
        *(ushort4*)(merged + (size_t)r * (2 * Dd) + Dd + t * 4) = ev;
    }
}

__global__ __launch_bounds__(256)
void gather_rms_merged(const int* __restrict__ xi, const float* __restrict__ table,
                       ushort* __restrict__ remb, ushort* __restrict__ merged) {
    __shared__ float reds[4];
    const int row = blockIdx.x;
    const int t = threadIdx.x;
    const int idx = xi[row];
    const float4 xv = *(const float4*)(table + (size_t)idx * Dd + t * 4);
    float q = xv.x*xv.x + xv.y*xv.y + xv.z*xv.z + xv.w*xv.w;
    for (int m = 32; m; m >>= 1) q += __shfl_xor(q, m);
    if ((t & 63) == 0) reds[t >> 6] = q;
    __syncthreads();
    q = reds[0] + reds[1] + reds[2] + reds[3];
    const float sc = rsqrtf(q * (1.f / Dd) + 1e-8f);
    ushort4 h;
    h.x = f2b(xv.x * sc); h.y = f2b(xv.y * sc); h.z = f2b(xv.z * sc); h.w = f2b(xv.w * sc);
    *(ushort4*)(remb + (size_t)row * Dd + t * 4) = h;
    const int b = row / Ss, s2 = row - b * Ss;
    if (s2 < Ii)
        *(ushort4*)(merged + (size_t)(b * Ii + s2) * (2 * Dd) + t * 4) = h;
    if (s2 >= 1 && s2 <= Ii)
        *(ushort4*)(merged + (size_t)(b * Ii + s2 - 1) * (2 * Dd) + Dd + t * 4) = h;
}

// ---------------- fallback f32-weight GEMM (round-1, proven) ----------------

__device__ inline bf16x8_t ld_frag(const ushort* p) {
    union { u64 l[2]; bf16x8_t s; } u;
    u.l[0] = *(const u64*)p;
    u.l[1] = *(const u64*)(p + 4);
    return u.s;
}

#define LDST 40

template<int KDIM, bool RELU, bool UNEMBED>
__global__ __launch_bounds__(256)
void gemm64(const ushort* __restrict__ A, const float* __restrict__ Wt,
            const float* __restrict__ bias, float* __restrict__ Cf,
            ushort* __restrict__ Cb, int Mrows, int N) {
    __shared__ ushort As[64 * LDST];
    __shared__ ushort Ws[64 * LDST];
    const int t    = threadIdx.x;
    const int tm0  = blockIdx.x * 64;
    const int tn0  = blockIdx.y * 64;
    const int lr   = t >> 2;
    const int lc   = (t & 3) * 8;
    const int wid  = t >> 6;
    const int lane = t & 63;
    const int wr   = (wid >> 1) * 32;
    const int wc   = (wid & 1) * 32;
    f32x4_t acc[2][2] = {};
    const bool avalid = (tm0 + lr) < Mrows;
    const ushort* Ap = A  + (size_t)(tm0 + lr) * KDIM + lc;
    const float*  Wp = Wt + (size_t)(tn0 + lr) * KDIM + lc;
    const int aoff = lr * LDST + lc;

    for (int k0 = 0; k0 < KDIM; k0 += 32) {
        union { uint4 qv; u64 l[2]; } av;
        av.qv = make_uint4(0u, 0u, 0u, 0u);
        if (avalid) av.qv = *(const uint4*)(Ap + k0);
        const float4 w0 = *(const float4*)(Wp + k0);
        const float4 w1 = *(const float4*)(Wp + k0 + 4);
        union { ushort us[8]; u64 l[2]; } wb;
        wb.us[0] = f2b(w0.x); wb.us[1] = f2b(w0.y); wb.us[2] = f2b(w0.z); wb.us[3] = f2b(w0.w);
        wb.us[4] = f2b(w1.x); wb.us[5] = f2b(w1.y); wb.us[6] = f2b(w1.z); wb.us[7] = f2b(w1.w);
        __syncthreads();
        *(u64*)&As[aoff]     = av.l[0];
        *(u64*)&As[aoff + 4] = av.l[1];
        *(u64*)&Ws[aoff]     = wb.l[0];
        *(u64*)&Ws[aoff + 4] = wb.l[1];
        __syncthreads();

        const ushort* ab = &As[(wr + (lane & 15)) * LDST + (lane >> 4) * 8];
        const ushort* bb = &Ws[(wc + (lane & 15)) * LDST + (lane >> 4) * 8];
        const bf16x8_t fa0 = ld_frag(ab);
        const bf16x8_t fa1 = ld_frag(ab + 16 * LDST);
        const bf16x8_t fb0 = ld_frag(bb);
        const bf16x8_t fb1 = ld_frag(bb + 16 * LDST);
        acc[0][0] = __builtin_amdgcn_mfma_f32_16x16x32_bf16(fa0, fb0, acc[0][0], 0, 0, 0);
        acc[0][1] = __builtin_amdgcn_mfma_f32_16x16x32_bf16(fa0, fb1, acc[0][1], 0, 0, 0);
        acc[1][0] = __builtin_amdgcn_mfma_f32_16x16x32_bf16(fa1, fb0, acc[1][0], 0, 0, 0);
        acc[1][1] = __builtin_amdgcn_mfma_f32_16x16x32_bf16(fa1, fb1, acc[1][1], 0, 0, 0);
    }

    const int rb = (lane >> 4) * 4;
    const int cl = lane & 15;
    for (int m = 0; m < 2; ++m)
        for (int n = 0; n < 2; ++n)
            for (int i = 0; i < 4; ++i) {
                const int r = tm0 + wr + m * 16 + rb + i;
                const int c = tn0 + wc + n * 16 + cl;
                if (r < Mrows) {
                    float v = acc[m][n][i];
                    if (bias) v += bias[c];
                    if (RELU) v = fmaxf(v, 0.f);
                    if (UNEMBED) {
                        const int kk  = r / Mm;
                        const int rem = r - kk * Mm;
                        Cf[(size_t)(rem * Kk + kk) * Vv + c] = v;
                    } else {
                        if (Cf) Cf[(size_t)r * N + c] = v;
                        if (Cb) Cb[(size_t)r * N + c] = f2b(v);
                    }
                }
            }
}

__global__ __launch_bounds__(256)
void ln_kernel(const float* __restrict__ a, const float* __restrict__ rsd,
               const float* __restrict__ g, const float* __restrict__ bb,
               float* __restrict__ outf, ushort* __restrict__ outb) {
    __shared__ float reds[8];
    const int row = blockIdx.x;
    const int t = threadIdx.x;
    const float4 xa = *(const float4*)(a   + (size_t)row * Dd + t * 4);
    const float4 xr = *(const float4*)(rsd + (size_t)row * Dd + t * 4);
    float x[4] = { xa.x + xr.x, xa.y + xr.y, xa.z + xr.z, xa.w + xr.w };
    float s = x[0] + x[1] + x[2] + x[3];
    float q = x[0]*x[0] + x[1]*x[1] + x[2]*x[2] + x[3]*x[3];
    for (int msk = 32; msk; msk >>= 1) { s += __shfl_xor(s, msk); q += __shfl_xor(q, msk); }
    if ((t & 63) == 0) { reds[t >> 6] = s; reds[4 + (t >> 6)] = q; }
    __syncthreads();
    s = reds[0] + reds[1] + reds[2] + reds[3];
    q = reds[4] + reds[5] + reds[6] + reds[7];
    const float m    = s * (1.f / Dd);
    const float var  = q * (1.f / Dd) - m * m;
    const float rstd = rsqrtf(var + 1e-5f);
    float y[4];
    #pragma unroll
    for (int j = 0; j < 4; ++j) {
        const int c = t * 4 + j;
        y[j] = (x[j] - m) * rstd * g[c] + bb[c];
    }
    if (outf) *(float4*)(outf + (size_t)row * Dd + t * 4) = make_float4(y[0], y[1], y[2], y[3]);
    if (outb) {
        ushort4 h; h.x = f2b(y[0]); h.y = f2b(y[1]); h.z = f2b(y[2]); h.w = f2b(y[3]);
        *(ushort4*)(outb + (size_t)row * Dd + t * 4) = h;
    }
}

__global__ __launch_bounds__(256)
void build_merged(const float* __restrict__ h, const ushort* __restrict__ remb,
                  ushort* __restrict__ merged, int k) {
    __shared__ float reds[4];
    const int r = blockIdx.x;
    const int t = threadIdx.x;
    const int b = r / Ii;
    const int i = r - b * Ii;
    if (k == 0) {
        const ushort4 hv = *(const ushort4*)(remb + (size_t)(b * Ss + i) * Dd + t * 4);
        *(ushort4*)(merged + (size_t)r * (2 * Dd) + t * 4) = hv;
    } else {
        const float4 xv = *(const float4*)(h + (size_t)r * Dd + t * 4);
        float q = xv.x*xv.x + xv.y*xv.y + xv.z*xv.z + xv.w*xv.w;
        for (int msk = 32; msk; msk >>= 1) q += __shfl_xor(q, msk);
        if ((t & 63) == 0) reds[t >> 6] = q;
        __syncthreads();
        q = reds[0] + reds[1] + reds[2] + reds[3];
        const float sc = rsqrtf(q * (1.f / Dd) + 1e-8f);
        ushort4 hv;
        hv.x = f2b(xv.x * sc); hv.y = f2b(xv.y * sc); hv.z = f2b(xv.z * sc); hv.w = f2b(xv.w * sc);
        *(ushort4*)(merged + (size_t)r * (2 * Dd) + t * 4) = hv;
    }
    const ushort4 ev = *(const ushort4*)(remb + (size_t)(b * Ss + k + 1 + i) * Dd + t * 4);
    *(ushort4*)(merged + (size_t)r * (2 * Dd) + Dd + t * 4) = ev;
}

__global__ __launch_bounds__(256)
void gather_rms(const int* __restrict__ xi, const float* __restrict__ table,
                ushort* __restrict__ remb) {
    __shared__ float reds[4];
    const int row = blockIdx.x;
    const int t = threadIdx.x;
    const int idx = xi[row];
    const float4 xv = *(const float4*)(table + (size_t)idx * Dd + t * 4);
    float q = xv.x*xv.x + xv.y*xv.y + xv.z*xv.z + xv.w*xv.w;
    for (int msk = 32; msk; msk >>= 1) q += __shfl_xor(q, msk);
    if ((t & 63) == 0) reds[t >> 6] = q;
    __syncthreads();
    q = reds[0] + reds[1] + reds[2] + reds[3];
    const float sc = rsqrtf(q * (1.f / Dd) + 1e-8f);
    ushort4 h;
    h.x = f2b(xv.x * sc); h.y = f2b(xv.y * sc); h.z = f2b(xv.z * sc); h.w = f2b(xv.w * sc);
    *(ushort4*)(remb + (size_t)row * Dd + t * 4) = h;
}

// ---------------- launcher ----------------

extern "C" void kernel_launch(void* const* d_in, const int* in_sizes, int n_in,
                              void* d_out, int out_size, void* d_ws, size_t ws_size,
                              hipStream_t stream) {
    const int*   x      = (const int*)  d_in[0];
    const float* table  = (const float*)d_in[1];
    const float* unemb  = (const float*)d_in[2];
    const float* proj_w = (const float*)d_in[3];
    const float* proj_b = (const float*)d_in[4];
    const float* sa_wv  = (const float*)d_in[5];
    const float* sa_bv  = (const float*)d_in[6];
    const float* sa_wo  = (const float*)d_in[7];
    const float* sa_bo  = (const float*)d_in[8];
    const float* ln1_g  = (const float*)d_in[9];
    const float* ln1_b  = (const float*)d_in[10];
    const float* ca_wv  = (const float*)d_in[11];
    const float* ca_bv  = (const float*)d_in[12];
    const float* ca_wo  = (const float*)d_in[13];
    const float* ca_bo  = (const float*)d_in[14];
    const float* ln2_g  = (const float*)d_in[15];
    const float* ln2_b  = (const float*)d_in[16];
    const float* ff_w1  = (const float*)d_in[17];
    const float* ff_b1  = (const float*)d_in[18];
    const float* ff_w2  = (const float*)d_in[19];
    const float* ff_b2  = (const float*)d_in[20];
    const float* ln3_g  = (const float*)d_in[21];
    const float* ln3_b  = (const float*)d_in[22];
    float* out = (float*)d_out;

    char* ws = (char*)d_ws;
    size_t off = 0;
    auto alloc = [&](size_t bytes) -> void* {
        void* p = ws + off;
        off = (off + bytes + 255) & ~(size_t)255;
        return p;
    };

    const size_t NEED = 262100000;

    if (ws_size >= NEED) {
        ushort* wU  = (ushort*)alloc((size_t)Vv * Dd * 2);
        ushort* wP  = (ushort*)alloc((size_t)Kk * Dd * 2 * Dd * 2);
        ushort* wV  = (ushort*)alloc((size_t)Kk * 2 * Dd * Dd * 2);
        ushort* wOs = (ushort*)alloc((size_t)Kk * Dd * Dd * 2);
        ushort* wOc = (ushort*)alloc((size_t)Kk * Dd * Dd * 2);
        ushort* wF1 = (ushort*)alloc((size_t)Kk * Ff * Dd * 2);
        ushort* wF2 = (ushort*)alloc((size_t)Kk * Dd * Ff * 2);
        float*  bV  = (float*) alloc((size_t)Kk * 2 * Dd * 4);
        ushort* remb   = (ushort*)alloc((size_t)Bz * Ss * Dd * 2);
        ushort* merged = (ushort*)alloc((size_t)Mp * 2 * Dd * 2);
        float*  xpf    = (float*) alloc((size_t)Mp * Dd * 4);
        ushort* xpb    = (ushort*)alloc((size_t)Mp * Dd * 2);
        ushort* tb     = (ushort*)alloc((size_t)Mp * 2 * Dd * 2);
        float*  sfa    = (float*) alloc((size_t)Mp * Dd * 4);
        float*  sfc    = (float*) alloc((size_t)Mp * Dd * 4);
        float*  x2f    = (float*) alloc((size_t)Mp * Dd * 4);
        ushort* x2b    = (ushort*)alloc((size_t)Mp * Dd * 2);
        ushort* x3all  = (ushort*)alloc((size_t)Mx * Dd * 2);

        const long nU = (long)Vv * Dd;
        convert_k<<<2048, 256, 0, stream>>>(unemb, wU, nU, nU, nU, 0);
        const long nP = (long)Kk * Dd * 2 * Dd;
        convert_k<<<2048, 256, 0, stream>>>(proj_w, wP, nP, nP, nP, 0);
        const long nDD = (long)Kk * Dd * Dd, pDD = (long)Dd * Dd, pV = 2 * pDD;
        convert_k<<<2048, 256, 0, stream>>>(sa_wv, wV, nDD, pDD, pV, 0);
        convert_k<<<2048, 256, 0, stream>>>(ca_wv, wV, nDD, pDD, pV, pDD);
        convert_k<<<2048, 256, 0, stream>>>(sa_wo, wOs, nDD, nDD, nDD, 0);
        convert_k<<<2048, 256, 0, stream>>>(ca_wo, wOc, nDD, nDD, nDD, 0);
        const long nF = (long)Kk * Ff * Dd;
        convert_k<<<2048, 256, 0, stream>>>(ff_w1, wF1, nF, nF, nF, 0);
        convert_k<<<2048, 256, 0, stream>>>(ff_w2, wF2, nF, nF, nF, 0);
        copyf_k<<<32, 256, 0, stream>>>(sa_bv, bV, (long)Kk * Dd, Dd, 2 * Dd, 0);
        copyf_k<<<32, 256, 0, stream>>>(ca_bv, bV, (long)Kk * Dd, Dd, 2 * Dd, Dd);

        gather_rms_merged<<<Bz * Ss, 256, 0, stream>>>(x, table, remb, merged);

        for (int k = 0; k < Kk; ++k) {
            gemm3<32, 64, 64, 256, 3, false, false><<<dim3(Mp/32, Dd/64, 1), 256, 0, stream>>>(
                merged, merged, 2 * Dd, wP + (size_t)k * Dd * 2 * Dd, wP + (size_t)k * Dd * 2 * Dd,
                proj_b + k * Dd, proj_b + k * Dd, xpf, xpf, xpb, xpb, Mm, Dd, 2 * Dd);
            gemm3<32, 64, 64, 256, 3, false, false><<<dim3(Mp/32, 2*Dd/64, 1), 256, 0, stream>>>(
                xpb, xpb, Dd, wV + (size_t)k * pV, wV + (size_t)k * pV,
                bV + (size_t)k * 2 * Dd, bV + (size_t)k * 2 * Dd,
                nullptr, nullptr, tb, tb, Mm, 2 * Dd, Dd);
            gemm3<32, 64, 64, 256, 3, false, false><<<dim3(Mp/32, Dd/64, 2), 256, 0, stream>>>(
                tb, tb + Dd, 2 * Dd, wOs + (size_t)k * pDD, wOc + (size_t)k * pDD,
                sa_bo + k * Dd, ca_bo + k * Dd, sfa, sfc, nullptr, nullptr, Mm, Dd, Dd);
            ln12_kernel<<<Mm, 256, 0, stream>>>(sfa, xpf, sfc,
                ln1_g + k * Dd, ln1_b + k * Dd, ln2_g + k * Dd, ln2_b + k * Dd, x2f, x2b);
            gemm3<32, 64, 64, 256, 3, true, false><<<dim3(Mp/32, Ff/64, 1), 256, 0, stream>>>(
                x2b, x2b, Dd, wF1 + (size_t)k * Ff * Dd, wF1 + (size_t)k * Ff * Dd,
                ff_b1 + k * Ff, ff_b1 + k * Ff, nullptr, nullptr, tb, tb, Mm, Ff, Dd);
            gemm3<32, 64, 64, 256, 3, false, false><<<dim3(Mp/32, Dd/64, 1), 256, 0, stream>>>(
                tb, tb, Ff, wF2 + (size_t)k * Dd * Ff, wF2 + (size_t)k * Dd * Ff,
                ff_b2 + k * Dd, ff_b2 + k * Dd, sfa, sfa, nullptr, nullptr, Mm, Dd, Ff);
            ln3m_kernel<<<Mm, 256, 0, stream>>>(sfa, x2f, ln3_g + k * Dd, ln3_b + k * Dd,
                remb, x3all + (size_t)k * Mm * Dd, merged, k);
        }

        // unembed: 32x32x16 MFMA, 256x256/BK=64, PF=2 counted-vmcnt + nt C-store
        gemm32<<<dim3(Mx/256, Vv/256, 1), 512, 0, stream>>>(x3all, wU, out, Mu, Dd);
        return;
    }

    // ---------------- fallback: round-1 proven f32-weight path ----------------
    ushort* remb   = (ushort*)alloc((size_t)Bz * Ss * Dd * 2);
    ushort* merged = (ushort*)alloc((size_t)Mm * 2 * Dd * 2);
    float*  xpf    = (float*) alloc((size_t)Mm * Dd * 4);
    ushort* xpb    = (ushort*)alloc((size_t)Mm * Dd * 2);
    ushort* tb     = (ushort*)alloc((size_t)Mm * Ff * 2);
    float*  sf     = (float*) alloc((size_t)Mm * Dd * 4);
    float*  x1f    = (float*) alloc((size_t)Mm * Dd * 4);
    float*  x2f    = (float*) alloc((size_t)Mm * Dd * 4);
    ushort* x2b    = (ushort*)alloc((size_t)Mm * Dd * 2);
    float*  hbuf   = (float*) alloc((size_t)Mm * Dd * 4);
    ushort* x3all  = (ushort*)alloc((size_t)Kk * Mm * Dd * 2);

    gather_rms<<<Bz * Ss, 256, 0, stream>>>(x, table, remb);

    const dim3 gD((Mm + 63) / 64, Dd / 64);
    const dim3 gF((Mm + 63) / 64, Ff / 64);
    for (int k = 0; k < Kk; ++k) {
        build_merged<<<Mm, 256, 0, stream>>>(hbuf, remb, merged, k);
        gemm64<2 * Dd, false, false><<<gD, 256, 0, stream>>>(
            merged, proj_w + (size_t)k * Dd * 2 * Dd, proj_b + k * Dd, xpf, xpb, Mm, Dd);
        gemm64<Dd, false, false><<<gD, 256, 0, stream>>>(
            xpb, sa_wv + (size_t)k * Dd * Dd, sa_bv + k * Dd, nullptr, tb, Mm, Dd);
        gemm64<Dd, false, false><<<gD, 256, 0, stream>>>(
            tb, sa_wo + (size_t)k * Dd * Dd, sa_bo + k * Dd, sf, nullptr, Mm, Dd);
        ln_kernel<<<Mm, 256, 0, stream>>>(sf, xpf, ln1_g + k * Dd, ln1_b + k * Dd, x1f, nullptr);
        gemm64<Dd, false, false><<<gD, 256, 0, stream>>>(
            xpb, ca_wv + (size_t)k * Dd * Dd, ca_bv + k * Dd, nullptr, tb, Mm, Dd);
        gemm64<Dd, false, false><<<gD, 256, 0, stream>>>(
            tb, ca_wo + (size_t)k * Dd * Dd, ca_bo + k * Dd, sf, nullptr, Mm, Dd);
        ln_kernel<<<Mm, 256, 0, stream>>>(sf, x1f, ln2_g + k * Dd, ln2_b + k * Dd, x2f, x2b);
        gemm64<Dd, true, false><<<gF, 256, 0, stream>>>(
            x2b, ff_w1 + (size_t)k * Ff * Dd, ff_b1 + k * Ff, nullptr, tb, Mm, Ff);
        gemm64<Ff, false, false><<<gD, 256, 0, stream>>>(
            tb, ff_w2 + (size_t)k * Dd * Ff, ff_b2 + k * Dd, sf, nullptr, Mm, Dd);
        ln_kernel<<<Mm, 256, 0, stream>>>(sf, x2f, ln3_g + k * Dd, ln3_b + k * Dd,
                                          hbuf, x3all + (size_t)k * Mm * Dd);
    }

    const dim3 gU((Kk * Mm) / 64, Vv / 64);
    gemm64<Dd, false, true><<<gU, 256, 0, stream>>>(x3all, unemb, nullptr, out, nullptr, Kk * Mm, Vv);
}